// Round 1
// baseline (984.609 us; speedup 1.0000x reference)
//
#include <hip/hip_runtime.h>
#include <hip/hip_bf16.h>
#include <cstdint>
#include <cstddef>

#define EPS 1e-5f

typedef __bf16 bf16;
typedef __bf16 bf16x4 __attribute__((ext_vector_type(4)));
typedef __bf16 bf16x8 __attribute__((ext_vector_type(8)));
typedef float f32x4 __attribute__((ext_vector_type(4)));

// ---------------------------------------------------------------- async copy
__device__ inline void async16(const void* g, void* l) {
  __builtin_amdgcn_global_load_lds(
      (const __attribute__((address_space(1))) void*)(uintptr_t)g,
      (__attribute__((address_space(3))) void*)(uint32_t)(uintptr_t)l,
      16, 0, 0);
}

__device__ inline f32x4 mfma_bf16(bf16x8 a, bf16x8 b, f32x4 c) {
  return __builtin_amdgcn_mfma_f32_16x16x32_bf16(a, b, c, 0, 0, 0);
}

// ---------------------------------------------------------------- GEMM
// C[M,N] = A[M,K] * BT[N,K]^T  (A,BT bf16 row-major; f32 accum; fused epilogues)
#define BM 128
#define BN 128
#define BK 32

enum { M_PLAIN = 0, M_EV = 1, M_E2 = 2, M_SILU = 3, M_MUL = 4,
       M_RESBF = 5, M_H2 = 6, M_RESF = 7 };

template <int MODE>
__global__ __launch_bounds__(256)
void gemm_bt(const bf16* __restrict__ A, const bf16* __restrict__ BT,
             void* __restrict__ outp, int M, int N, int K,
             const void* __restrict__ aux0, const float* __restrict__ aux1,
             const float* __restrict__ qkv) {
  __shared__ bf16 a_lds[BM * BK];
  __shared__ bf16 b_lds[BN * BK];
  const int tid = threadIdx.x;
  const int wave = tid >> 6, lane = tid & 63;
  const int m0 = blockIdx.x * BM, n0 = blockIdx.y * BN;

  const bf16* Ab = A + (size_t)m0 * K;
  const bf16* Bb = BT + (size_t)n0 * K;

  const int srow = tid >> 2;        // 0..63
  const int scol = (tid & 3) * 8;   // 0,8,16,24
  bf16* a_dst0 = &a_lds[(wave * 64) * 8];
  bf16* a_dst1 = &a_lds[(256 + wave * 64) * 8];
  bf16* b_dst0 = &b_lds[(wave * 64) * 8];
  bf16* b_dst1 = &b_lds[(256 + wave * 64) * 8];

  f32x4 acc[4][4] = {};

  const int wm = (wave >> 1) * 64, wn = (wave & 1) * 64;
  const int fr = lane & 15, fq = lane >> 4;

  for (int kt = 0; kt < K; kt += BK) {
    async16(Ab + (size_t)srow * K + kt + scol, a_dst0);
    async16(Ab + (size_t)(srow + 64) * K + kt + scol, a_dst1);
    async16(Bb + (size_t)srow * K + kt + scol, b_dst0);
    async16(Bb + (size_t)(srow + 64) * K + kt + scol, b_dst1);
    __syncthreads();
    bf16x8 af[4], bfv[4];
#pragma unroll
    for (int t = 0; t < 4; ++t) {
      af[t]  = *(const bf16x8*)&a_lds[(wm + t * 16 + fr) * BK + fq * 8];
      bfv[t] = *(const bf16x8*)&b_lds[(wn + t * 16 + fr) * BK + fq * 8];
    }
#pragma unroll
    for (int mt = 0; mt < 4; ++mt)
#pragma unroll
      for (int nt = 0; nt < 4; ++nt)
        acc[mt][nt] = mfma_bf16(af[mt], bfv[nt], acc[mt][nt]);
    __syncthreads();
  }

#pragma unroll
  for (int mt = 0; mt < 4; ++mt) {
#pragma unroll
    for (int r = 0; r < 4; ++r) {
      const int row = m0 + wm + mt * 16 + fq * 4 + r;
#pragma unroll
      for (int nt = 0; nt < 4; ++nt) {
        const int col = n0 + wn + nt * 16 + fr;
        float v = acc[mt][nt][r];
        const size_t oi = (size_t)row * N + col;
        if (MODE == M_PLAIN) {
          ((float*)outp)[oi] = v;
        } else if (MODE == M_EV) {
          // row = ((b*128+i)*128+j); add Ni[b,i,col] + Nj[b,j,col]
          const int bi = row >> 7, b = row >> 14, j = row & 127;
          v += qkv[bi * 2560 + 1536 + col] + qkv[(b * 128 + j) * 2560 + 2048 + col];
          ((bf16*)outp)[oi] = (bf16)v;
        } else if (MODE == M_E2) {
          v += (float)((const bf16*)aux0)[oi] + aux1[col];
          ((bf16*)outp)[oi] = (bf16)v;
        } else if (MODE == M_SILU) {
          v = v / (1.f + __expf(-v));
          ((bf16*)outp)[oi] = (bf16)v;
        } else if (MODE == M_MUL) {
          v *= (float)((const bf16*)aux0)[oi];
          ((bf16*)outp)[oi] = (bf16)v;
        } else if (MODE == M_RESBF) {
          ((float*)outp)[oi] = v + (float)((const bf16*)aux0)[oi];
        } else if (MODE == M_H2) {
          ((float*)outp)[oi] = v + ((const float*)aux0)[oi] + aux1[col];
        } else if (MODE == M_RESF) {
          ((float*)outp)[oi] = v + ((const float*)aux0)[oi];
        }
      }
    }
  }
}

// ---------------------------------------------------------------- transpose W (K,N) f32 -> (N,K) bf16
__global__ __launch_bounds__(256)
void transpose_to_bf16(const float* __restrict__ in, bf16* __restrict__ out,
                       int K, int N) {
  __shared__ float t[32][33];
  const int bk = blockIdx.x * 32, bn = blockIdx.y * 32;
  const int tx = threadIdx.x & 31, ty = threadIdx.x >> 5;  // 32 x 8
#pragma unroll
  for (int r = 0; r < 32; r += 8)
    t[ty + r][tx] = in[(size_t)(bk + ty + r) * N + bn + tx];
  __syncthreads();
#pragma unroll
  for (int r = 0; r < 32; r += 8)
    out[(size_t)(bn + ty + r) * K + bk + tx] = (bf16)t[tx][ty + r];
}

// ---------------------------------------------------------------- batchnorm over 256 rows x 512 ch
__global__ __launch_bounds__(64)
void batchnorm_k(const float* __restrict__ x, const float* __restrict__ g,
                 const float* __restrict__ bta, float* __restrict__ y_f,
                 bf16* __restrict__ y_b) {
  const int c = blockIdx.x * 64 + threadIdx.x;
  float s = 0.f, q = 0.f;
  for (int r = 0; r < 256; ++r) {
    const float v = x[r * 512 + c];
    s += v; q += v * v;
  }
  const float mean = s * (1.f / 256.f);
  const float rstd = rsqrtf(q * (1.f / 256.f) - mean * mean + EPS);
  const float sc = g[c] * rstd, sh = bta[c] - mean * sc;
  for (int r = 0; r < 256; ++r) {
    const float v = x[r * 512 + c] * sc + sh;
    if (y_f) y_f[r * 512 + c] = v;
    y_b[r * 512 + c] = (bf16)v;
  }
}

// ---------------------------------------------------------------- layernorm rows of 512
template <int IN_BF>
__global__ __launch_bounds__(128)
void layernorm_k(const void* __restrict__ xin, const float* __restrict__ g,
                 const float* __restrict__ bta, bf16* __restrict__ yout) {
  const size_t row = blockIdx.x;
  const int tid = threadIdx.x;
  float v[4];
  if (IN_BF) {
    const bf16x4 t = *((const bf16x4*)((const bf16*)xin + row * 512) + tid);
    v[0] = (float)t[0]; v[1] = (float)t[1]; v[2] = (float)t[2]; v[3] = (float)t[3];
  } else {
    const float4 t = *((const float4*)((const float*)xin + row * 512) + tid);
    v[0] = t.x; v[1] = t.y; v[2] = t.z; v[3] = t.w;
  }
  float s = v[0] + v[1] + v[2] + v[3];
  float q = v[0] * v[0] + v[1] * v[1] + v[2] * v[2] + v[3] * v[3];
  for (int o = 32; o > 0; o >>= 1) { s += __shfl_xor(s, o); q += __shfl_xor(q, o); }
  __shared__ float sm[4];
  if ((tid & 63) == 0) { sm[(tid >> 6) * 2] = s; sm[(tid >> 6) * 2 + 1] = q; }
  __syncthreads();
  s = sm[0] + sm[2]; q = sm[1] + sm[3];
  const float mean = s * (1.f / 512.f);
  const float rstd = rsqrtf(q * (1.f / 512.f) - mean * mean + EPS);
  const float4 gg = *((const float4*)g + tid);
  const float4 bb = *((const float4*)bta + tid);
  bf16x4 o4;
  o4[0] = (bf16)((v[0] - mean) * rstd * gg.x + bb.x);
  o4[1] = (bf16)((v[1] - mean) * rstd * gg.y + bb.y);
  o4[2] = (bf16)((v[2] - mean) * rstd * gg.z + bb.z);
  o4[3] = (bf16)((v[3] - mean) * rstd * gg.w + bb.w);
  *((bf16x4*)(yout + row * 512) + tid) = o4;
}

// ---------------------------------------------------------------- attention: one wave per (b,h,i)
__global__ __launch_bounds__(64)
void attn_k(const bf16* __restrict__ ev, const float* __restrict__ qkv,
            bf16* __restrict__ outp) {
  const int i = blockIdx.x & 127, h = (blockIdx.x >> 7) & 7, b = blockIdx.x >> 10;
  const int lane = threadIdx.x;
  const int bi = b * 128 + i;
  const int hc = h * 64 + lane;
  const float qv = qkv[bi * 2560 + hc];
  __shared__ float sc[128];
  const bf16* evr = ev + (size_t)bi * 128 * 512 + h * 64;
  for (int j = 0; j < 128; ++j) {
    float p = qv * (float)evr[(size_t)j * 512 + lane] *
              qkv[(b * 128 + j) * 2560 + 512 + hc];
    for (int o = 32; o > 0; o >>= 1) p += __shfl_xor(p, o);
    if (lane == 0) sc[j] = p * 0.125f;  // 1/sqrt(64)
  }
  __syncthreads();
  float s0 = sc[lane], s1 = sc[lane + 64];
  float mx = fmaxf(s0, s1);
  for (int o = 32; o > 0; o >>= 1) mx = fmaxf(mx, __shfl_xor(mx, o));
  const float e0 = __expf(s0 - mx), e1 = __expf(s1 - mx);
  float sum = e0 + e1;
  for (int o = 32; o > 0; o >>= 1) sum += __shfl_xor(sum, o);
  const float inv = 1.f / sum;
  sc[lane] = e0 * inv; sc[lane + 64] = e1 * inv;
  __syncthreads();
  float acc = 0.f;
  for (int j = 0; j < 128; ++j)
    acc += sc[j] * qkv[(b * 128 + j) * 2560 + 1024 + hc];
  outp[(size_t)bi * 512 + hc] = (bf16)acc;
}

// ---------------------------------------------------------------- symmetrize lower triangle in place
__global__ __launch_bounds__(256)
void sym_k(float* __restrict__ e) {
  const int i = blockIdx.y + 1;
  const int b = blockIdx.z;
  const int idx = blockIdx.x * 256 + threadIdx.x;  // j*512 + c
  const int j = idx >> 9;
  if (j >= i) return;
  const int c = idx & 511;
  const size_t lo = (((size_t)(b * 128 + i) * 128) + j) * 512 + c;
  const size_t up = (((size_t)(b * 128 + j) * 128) + i) * 512 + c;
  const float u = e[up];
  if (u != 0.0f) e[lo] = u;
}

// ---------------------------------------------------------------- launch
extern "C" void kernel_launch(void* const* d_in, const int* in_sizes, int n_in,
                              void* d_out, int out_size, void* d_ws, size_t ws_size,
                              hipStream_t stream) {
  const float* h_in = (const float*)d_in[0];
  const float* e_in = (const float*)d_in[1];
  const float* Wq   = (const float*)d_in[2];
  const float* Wk   = (const float*)d_in[3];
  const float* Wv   = (const float*)d_in[4];
  const float* We   = (const float*)d_in[5];
  const float* Wni  = (const float*)d_in[6];
  const float* Wnj  = (const float*)d_in[7];
  const float* Woh  = (const float*)d_in[8];
  const float* boh  = (const float*)d_in[9];
  const float* Woe  = (const float*)d_in[10];
  const float* boe  = (const float*)d_in[11];
  const float* bn1g = (const float*)d_in[12];
  const float* bn1b = (const float*)d_in[13];
  const float* bn2g = (const float*)d_in[14];
  const float* bn2b = (const float*)d_in[15];
  const float* ln1g = (const float*)d_in[16];
  const float* ln1b = (const float*)d_in[17];
  const float* ln2g = (const float*)d_in[18];
  const float* ln2b = (const float*)d_in[19];
  const float* fhw1 = (const float*)d_in[20];
  const float* fhw3 = (const float*)d_in[21];
  const float* fhw2 = (const float*)d_in[22];
  const float* few1 = (const float*)d_in[23];
  const float* few3 = (const float*)d_in[24];
  const float* few2 = (const float*)d_in[25];

  char* ws = (char*)d_ws;
  size_t off = 0;
  auto alloc = [&](size_t bytes) -> void* {
    void* p = ws + off;
    off = (off + bytes + 255) & ~(size_t)255;
    return p;
  };

  bf16* qkvT = (bf16*)alloc((size_t)2560 * 512 * 2);
  bf16* WeT  = (bf16*)alloc((size_t)512 * 512 * 2);
  bf16* WohT = (bf16*)alloc((size_t)512 * 512 * 2);
  bf16* WoeT = (bf16*)alloc((size_t)512 * 512 * 2);
  bf16* fh1T = (bf16*)alloc((size_t)2048 * 512 * 2);
  bf16* fh3T = (bf16*)alloc((size_t)2048 * 512 * 2);
  bf16* fh2T = (bf16*)alloc((size_t)512 * 2048 * 2);
  bf16* fe1T = (bf16*)alloc((size_t)2048 * 512 * 2);
  bf16* fe3T = (bf16*)alloc((size_t)2048 * 512 * 2);
  bf16* fe2T = (bf16*)alloc((size_t)512 * 2048 * 2);
  float* h1f = (float*)alloc((size_t)256 * 512 * 4);
  bf16* h1b  = (bf16*)alloc((size_t)256 * 512 * 2);
  float* qkv = (float*)alloc((size_t)256 * 2560 * 4);
  float* h2f = (float*)alloc((size_t)256 * 512 * 4);
  bf16* hxb  = (bf16*)alloc((size_t)256 * 512 * 2);
  bf16* aob  = (bf16*)alloc((size_t)256 * 512 * 2);
  bf16* shb  = (bf16*)alloc((size_t)256 * 2048 * 2);
  bf16* uhb  = (bf16*)alloc((size_t)256 * 2048 * 2);
  const size_t ER = (size_t)32768 * 512;
  bf16* e1b = (bf16*)alloc(ER * 2);  // e1, later reused as x = LN2(e2)
  bf16* evb = (bf16*)alloc(ER * 2);  // ev, later reused as SiLU scratch
  bf16* e2b = (bf16*)alloc(ER * 2);
  int R = 8192;
  while (R > 1024 && off + (size_t)R * 2048 * 2 > ws_size) R >>= 1;
  bf16* ub = (bf16*)alloc((size_t)R * 2048 * 2);

  float* outh = (float*)d_out;
  float* oute = (float*)d_out + 131072;

  auto tr = [&](const float* w, bf16* o, int K, int N) {
    transpose_to_bf16<<<dim3(K / 32, N / 32), 256, 0, stream>>>(w, o, K, N);
  };
  tr(Wq,  qkvT + (size_t)0 * 512 * 512, 512, 512);
  tr(Wk,  qkvT + (size_t)1 * 512 * 512, 512, 512);
  tr(Wv,  qkvT + (size_t)2 * 512 * 512, 512, 512);
  tr(Wni, qkvT + (size_t)3 * 512 * 512, 512, 512);
  tr(Wnj, qkvT + (size_t)4 * 512 * 512, 512, 512);
  tr(We,  WeT,  512, 512);
  tr(Woh, WohT, 512, 512);
  tr(Woe, WoeT, 512, 512);
  tr(fhw1, fh1T, 512, 2048);
  tr(fhw3, fh3T, 512, 2048);
  tr(fhw2, fh2T, 2048, 512);
  tr(few1, fe1T, 512, 2048);
  tr(few3, fe3T, 512, 2048);
  tr(few2, fe2T, 2048, 512);

  // h path front: bn1 -> h1; fused QKV/Ni/Nj projection
  batchnorm_k<<<8, 64, 0, stream>>>(h_in, bn1g, bn1b, h1f, h1b);
  gemm_bt<M_PLAIN><<<dim3(2, 20), 256, 0, stream>>>(
      h1b, qkvT, qkv, 256, 2560, 512, nullptr, nullptr, nullptr);

  // e path: ln1 -> ev = e1@We + Ni + Nj
  layernorm_k<0><<<32768, 128, 0, stream>>>(e_in, ln1g, ln1b, e1b);
  gemm_bt<M_EV><<<dim3(256, 4), 256, 0, stream>>>(
      e1b, WeT, evb, 32768, 512, 512, nullptr, nullptr, qkv);

  // attention -> h2 = h1 + attn@Woh + boh
  attn_k<<<2048, 64, 0, stream>>>(evb, qkv, aob);
  gemm_bt<M_H2><<<dim3(2, 4), 256, 0, stream>>>(
      aob, WohT, h2f, 256, 512, 512, h1f, boh, nullptr);

  // h FFN: bn2 -> swiglu -> out_h = h2 + ffn
  batchnorm_k<<<8, 64, 0, stream>>>(h2f, bn2g, bn2b, nullptr, hxb);
  gemm_bt<M_SILU><<<dim3(2, 16), 256, 0, stream>>>(
      hxb, fh1T, shb, 256, 2048, 512, nullptr, nullptr, nullptr);
  gemm_bt<M_MUL><<<dim3(2, 16), 256, 0, stream>>>(
      hxb, fh3T, uhb, 256, 2048, 512, shb, nullptr, nullptr);
  gemm_bt<M_RESF><<<dim3(2, 4), 256, 0, stream>>>(
      uhb, fh2T, outh, 256, 512, 2048, h2f, nullptr, nullptr);

  // e2 = e1 + ev@Woe + boe
  gemm_bt<M_E2><<<dim3(256, 4), 256, 0, stream>>>(
      evb, WoeT, e2b, 32768, 512, 512, e1b, boe, nullptr);

  // e FFN: ln2 -> swiglu (chunked) -> out_e = e2 + ffn
  layernorm_k<1><<<32768, 128, 0, stream>>>(e2b, ln2g, ln2b, e1b);
  for (int c = 0; c * R < 32768; ++c) {
    bf16* xA = e1b + (size_t)c * R * 512;
    gemm_bt<M_SILU><<<dim3(R / 128, 16), 256, 0, stream>>>(
        xA, fe1T, evb, R, 2048, 512, nullptr, nullptr, nullptr);
    gemm_bt<M_MUL><<<dim3(R / 128, 16), 256, 0, stream>>>(
        xA, fe3T, ub, R, 2048, 512, evb, nullptr, nullptr);
    gemm_bt<M_RESBF><<<dim3(R / 128, 4), 256, 0, stream>>>(
        ub, fe2T, oute + (size_t)c * R * 512, R, 512, 2048,
        e2b + (size_t)c * R * 512, nullptr, nullptr);
  }

  sym_k<<<dim3(254, 127, 2), 256, 0, stream>>>(oute);
}

// Round 2
// 955.921 us; speedup vs baseline: 1.0300x; 1.0300x over previous
//
#include <hip/hip_runtime.h>
#include <hip/hip_bf16.h>
#include <cstdint>
#include <cstddef>

#define EPS 1e-5f

typedef __bf16 bf16;
typedef __bf16 bf16x4 __attribute__((ext_vector_type(4)));
typedef __bf16 bf16x8 __attribute__((ext_vector_type(8)));
typedef float f32x4 __attribute__((ext_vector_type(4)));

// ---------------------------------------------------------------- async copy
__device__ inline void async16(const void* g, void* l) {
  __builtin_amdgcn_global_load_lds(
      (const __attribute__((address_space(1))) void*)(uintptr_t)g,
      (__attribute__((address_space(3))) void*)(uint32_t)(uintptr_t)l,
      16, 0, 0);
}

__device__ inline f32x4 mfma_bf16(bf16x8 a, bf16x8 b, f32x4 c) {
  return __builtin_amdgcn_mfma_f32_16x16x32_bf16(a, b, c, 0, 0, 0);
}

// ---------------------------------------------------------------- GEMM
#define BM 128
#define BN 128
#define BK 32

enum { M_PLAIN = 0, M_EV = 1, M_E2 = 2, M_RESBF = 5, M_H2 = 6, M_RESF = 7 };

template <int MODE>
__global__ __launch_bounds__(256)
void gemm_bt(const bf16* __restrict__ A, const bf16* __restrict__ BT,
             void* __restrict__ outp, int M, int N, int K,
             const void* __restrict__ aux0, const float* __restrict__ aux1,
             const float* __restrict__ qkv) {
  __shared__ bf16 a_lds[BM * BK];
  __shared__ bf16 b_lds[BN * BK];
  const int tid = threadIdx.x;
  const int wave = tid >> 6, lane = tid & 63;
  const int m0 = blockIdx.x * BM, n0 = blockIdx.y * BN;

  const bf16* Ab = A + (size_t)m0 * K;
  const bf16* Bb = BT + (size_t)n0 * K;

  const int srow = tid >> 2;        // 0..63
  const int scol = (tid & 3) * 8;   // 0,8,16,24
  bf16* a_dst0 = &a_lds[(wave * 64) * 8];
  bf16* a_dst1 = &a_lds[(256 + wave * 64) * 8];
  bf16* b_dst0 = &b_lds[(wave * 64) * 8];
  bf16* b_dst1 = &b_lds[(256 + wave * 64) * 8];

  f32x4 acc[4][4] = {};

  const int wm = (wave >> 1) * 64, wn = (wave & 1) * 64;
  const int fr = lane & 15, fq = lane >> 4;

  for (int kt = 0; kt < K; kt += BK) {
    async16(Ab + (size_t)srow * K + kt + scol, a_dst0);
    async16(Ab + (size_t)(srow + 64) * K + kt + scol, a_dst1);
    async16(Bb + (size_t)srow * K + kt + scol, b_dst0);
    async16(Bb + (size_t)(srow + 64) * K + kt + scol, b_dst1);
    __syncthreads();
    bf16x8 af[4], bfv[4];
#pragma unroll
    for (int t = 0; t < 4; ++t) {
      af[t]  = *(const bf16x8*)&a_lds[(wm + t * 16 + fr) * BK + fq * 8];
      bfv[t] = *(const bf16x8*)&b_lds[(wn + t * 16 + fr) * BK + fq * 8];
    }
#pragma unroll
    for (int mt = 0; mt < 4; ++mt)
#pragma unroll
      for (int nt = 0; nt < 4; ++nt)
        acc[mt][nt] = mfma_bf16(af[mt], bfv[nt], acc[mt][nt]);
    __syncthreads();
  }

#pragma unroll
  for (int mt = 0; mt < 4; ++mt) {
#pragma unroll
    for (int r = 0; r < 4; ++r) {
      const int row = m0 + wm + mt * 16 + fq * 4 + r;
#pragma unroll
      for (int nt = 0; nt < 4; ++nt) {
        const int col = n0 + wn + nt * 16 + fr;
        float v = acc[mt][nt][r];
        const size_t oi = (size_t)row * N + col;
        if (MODE == M_PLAIN) {
          ((float*)outp)[oi] = v;
        } else if (MODE == M_EV) {
          const int bi = row >> 7, b = row >> 14, j = row & 127;
          v += qkv[bi * 2560 + 1536 + col] + qkv[(b * 128 + j) * 2560 + 2048 + col];
          ((bf16*)outp)[oi] = (bf16)v;
        } else if (MODE == M_E2) {
          v += (float)((const bf16*)aux0)[oi] + aux1[col];
          ((bf16*)outp)[oi] = (bf16)v;
        } else if (MODE == M_RESBF) {
          ((float*)outp)[oi] = v + (float)((const bf16*)aux0)[oi];
        } else if (MODE == M_H2) {
          ((float*)outp)[oi] = v + ((const float*)aux0)[oi] + aux1[col];
        } else if (MODE == M_RESF) {
          ((float*)outp)[oi] = v + ((const float*)aux0)[oi];
        }
      }
    }
  }
}

// ---------------------------------------------------------------- dual-B SwiGLU GEMM
// out[M,N] = silu(A@B1T^T) * (A@B2T^T), bf16 out
__global__ __launch_bounds__(256)
void gemm_dual(const bf16* __restrict__ A, const bf16* __restrict__ B1T,
               const bf16* __restrict__ B2T, bf16* __restrict__ outp,
               int M, int N, int K) {
  __shared__ bf16 a_lds[BM * BK];
  __shared__ bf16 b1_lds[BN * BK];
  __shared__ bf16 b2_lds[BN * BK];
  const int tid = threadIdx.x;
  const int wave = tid >> 6, lane = tid & 63;
  const int m0 = blockIdx.x * BM, n0 = blockIdx.y * BN;

  const bf16* Ab = A + (size_t)m0 * K;
  const bf16* B1b = B1T + (size_t)n0 * K;
  const bf16* B2b = B2T + (size_t)n0 * K;

  const int srow = tid >> 2;
  const int scol = (tid & 3) * 8;
  bf16* a_d0 = &a_lds[(wave * 64) * 8];
  bf16* a_d1 = &a_lds[(256 + wave * 64) * 8];
  bf16* b1_d0 = &b1_lds[(wave * 64) * 8];
  bf16* b1_d1 = &b1_lds[(256 + wave * 64) * 8];
  bf16* b2_d0 = &b2_lds[(wave * 64) * 8];
  bf16* b2_d1 = &b2_lds[(256 + wave * 64) * 8];

  f32x4 acc1[4][4] = {};
  f32x4 acc2[4][4] = {};

  const int wm = (wave >> 1) * 64, wn = (wave & 1) * 64;
  const int fr = lane & 15, fq = lane >> 4;

  for (int kt = 0; kt < K; kt += BK) {
    async16(Ab + (size_t)srow * K + kt + scol, a_d0);
    async16(Ab + (size_t)(srow + 64) * K + kt + scol, a_d1);
    async16(B1b + (size_t)srow * K + kt + scol, b1_d0);
    async16(B1b + (size_t)(srow + 64) * K + kt + scol, b1_d1);
    async16(B2b + (size_t)srow * K + kt + scol, b2_d0);
    async16(B2b + (size_t)(srow + 64) * K + kt + scol, b2_d1);
    __syncthreads();
    bf16x8 af[4], b1f[4], b2f[4];
#pragma unroll
    for (int t = 0; t < 4; ++t) {
      af[t]  = *(const bf16x8*)&a_lds[(wm + t * 16 + fr) * BK + fq * 8];
      b1f[t] = *(const bf16x8*)&b1_lds[(wn + t * 16 + fr) * BK + fq * 8];
      b2f[t] = *(const bf16x8*)&b2_lds[(wn + t * 16 + fr) * BK + fq * 8];
    }
#pragma unroll
    for (int mt = 0; mt < 4; ++mt)
#pragma unroll
      for (int nt = 0; nt < 4; ++nt) {
        acc1[mt][nt] = mfma_bf16(af[mt], b1f[nt], acc1[mt][nt]);
        acc2[mt][nt] = mfma_bf16(af[mt], b2f[nt], acc2[mt][nt]);
      }
    __syncthreads();
  }

#pragma unroll
  for (int mt = 0; mt < 4; ++mt) {
#pragma unroll
    for (int r = 0; r < 4; ++r) {
      const int row = m0 + wm + mt * 16 + fq * 4 + r;
#pragma unroll
      for (int nt = 0; nt < 4; ++nt) {
        const int col = n0 + wn + nt * 16 + fr;
        const float c1 = acc1[mt][nt][r];
        const float c2 = acc2[mt][nt][r];
        const float v = c1 / (1.f + __expf(-c1)) * c2;
        outp[(size_t)row * N + col] = (bf16)v;
      }
    }
  }
}

// ---------------------------------------------------------------- batched transpose
struct TrJobs {
  const float* src[14];
  bf16* dst[14];
  int K[14];
  int N[14];
};

__global__ __launch_bounds__(256)
void transpose_all(TrJobs jobs) {
  const int w = blockIdx.y;
  const int K = jobs.K[w], N = jobs.N[w];
  const int tilesK = K >> 5;
  const int tiles = tilesK * (N >> 5);
  const int t0 = blockIdx.x;
  if (t0 >= tiles) return;
  const int bk = (t0 % tilesK) * 32, bn = (t0 / tilesK) * 32;
  const float* __restrict__ in = jobs.src[w];
  bf16* __restrict__ out = jobs.dst[w];
  __shared__ float t[32][33];
  const int tx = threadIdx.x & 31, ty = threadIdx.x >> 5;  // 32 x 8
#pragma unroll
  for (int r = 0; r < 32; r += 8)
    t[ty + r][tx] = in[(size_t)(bk + ty + r) * N + bn + tx];
  __syncthreads();
#pragma unroll
  for (int r = 0; r < 32; r += 8)
    out[(size_t)(bn + ty + r) * K + bk + tx] = (bf16)t[tx][ty + r];
}

// ---------------------------------------------------------------- batchnorm over 256 rows x 512 ch
__global__ __launch_bounds__(64)
void batchnorm_k(const float* __restrict__ x, const float* __restrict__ g,
                 const float* __restrict__ bta, float* __restrict__ y_f,
                 bf16* __restrict__ y_b) {
  const int c = blockIdx.x * 64 + threadIdx.x;
  float s = 0.f, q = 0.f;
  for (int r = 0; r < 256; ++r) {
    const float v = x[r * 512 + c];
    s += v; q += v * v;
  }
  const float mean = s * (1.f / 256.f);
  const float rstd = rsqrtf(q * (1.f / 256.f) - mean * mean + EPS);
  const float sc = g[c] * rstd, sh = bta[c] - mean * sc;
  for (int r = 0; r < 256; ++r) {
    const float v = x[r * 512 + c] * sc + sh;
    if (y_f) y_f[r * 512 + c] = v;
    y_b[r * 512 + c] = (bf16)v;
  }
}

// ---------------------------------------------------------------- layernorm rows of 512
template <int IN_BF>
__global__ __launch_bounds__(128)
void layernorm_k(const void* __restrict__ xin, const float* __restrict__ g,
                 const float* __restrict__ bta, bf16* __restrict__ yout) {
  const size_t row = blockIdx.x;
  const int tid = threadIdx.x;
  float v[4];
  if (IN_BF) {
    const bf16x4 t = *((const bf16x4*)((const bf16*)xin + row * 512) + tid);
    v[0] = (float)t[0]; v[1] = (float)t[1]; v[2] = (float)t[2]; v[3] = (float)t[3];
  } else {
    const float4 t = *((const float4*)((const float*)xin + row * 512) + tid);
    v[0] = t.x; v[1] = t.y; v[2] = t.z; v[3] = t.w;
  }
  float s = v[0] + v[1] + v[2] + v[3];
  float q = v[0] * v[0] + v[1] * v[1] + v[2] * v[2] + v[3] * v[3];
  for (int o = 32; o > 0; o >>= 1) { s += __shfl_xor(s, o); q += __shfl_xor(q, o); }
  __shared__ float sm[4];
  if ((tid & 63) == 0) { sm[(tid >> 6) * 2] = s; sm[(tid >> 6) * 2 + 1] = q; }
  __syncthreads();
  s = sm[0] + sm[2]; q = sm[1] + sm[3];
  const float mean = s * (1.f / 512.f);
  const float rstd = rsqrtf(q * (1.f / 512.f) - mean * mean + EPS);
  const float4 gg = *((const float4*)g + tid);
  const float4 bb = *((const float4*)bta + tid);
  bf16x4 o4;
  o4[0] = (bf16)((v[0] - mean) * rstd * gg.x + bb.x);
  o4[1] = (bf16)((v[1] - mean) * rstd * gg.y + bb.y);
  o4[2] = (bf16)((v[2] - mean) * rstd * gg.z + bb.z);
  o4[3] = (bf16)((v[3] - mean) * rstd * gg.w + bb.w);
  *((bf16x4*)(yout + row * 512) + tid) = o4;
}

// ---------------------------------------------------------------- attention v2: 256 threads per (b,h,i)
__global__ __launch_bounds__(256)
void attn_k(const bf16* __restrict__ ev, const float* __restrict__ qkv,
            bf16* __restrict__ outp) {
  const int i = blockIdx.x & 127, h = (blockIdx.x >> 7) & 7, b = blockIdx.x >> 10;
  const int bi = b * 128 + i;
  const int tid = threadIdx.x;
  __shared__ float sc[256];
  __shared__ float wt[128];
  // phase 1: partial scores — thread (j, d-half)
  {
    const int j = tid & 127, half = tid >> 7;
    const bf16* evp = ev + (size_t)bi * 65536 + (size_t)j * 512 + h * 64 + half * 32;
    const float* qp = qkv + bi * 2560 + h * 64 + half * 32;
    const float* kp = qkv + (b * 128 + j) * 2560 + 512 + h * 64 + half * 32;
    float p = 0.f;
#pragma unroll
    for (int t = 0; t < 4; ++t) {
      const bf16x8 e8 = *(const bf16x8*)(evp + t * 8);
#pragma unroll
      for (int u = 0; u < 8; ++u)
        p += qp[t * 8 + u] * (float)e8[u] * kp[t * 8 + u];
    }
    sc[half * 128 + j] = p;
  }
  __syncthreads();
  // phase 2: softmax over 128 j, wave 0 only
  if (tid < 64) {
    const float s0 = (sc[tid] + sc[128 + tid]) * 0.125f;        // 1/sqrt(64)
    const float s1 = (sc[64 + tid] + sc[192 + tid]) * 0.125f;
    float mx = fmaxf(s0, s1);
    for (int o = 32; o > 0; o >>= 1) mx = fmaxf(mx, __shfl_xor(mx, o));
    const float e0 = __expf(s0 - mx), e1 = __expf(s1 - mx);
    float sum = e0 + e1;
    for (int o = 32; o > 0; o >>= 1) sum += __shfl_xor(sum, o);
    const float inv = 1.f / sum;
    wt[tid] = e0 * inv; wt[64 + tid] = e1 * inv;
  }
  __syncthreads();
  // phase 3: out[d] = sum_j wt[j]*v[j,d] — thread (d, j-quarter)
  {
    const int d = tid & 63, jq = tid >> 6;
    const float* vp = qkv + (b * 128 + jq * 32) * 2560 + 1024 + h * 64 + d;
    float acc = 0.f;
#pragma unroll
    for (int j = 0; j < 32; ++j)
      acc += wt[jq * 32 + j] * vp[(size_t)j * 2560];
    sc[tid] = acc;
  }
  __syncthreads();
  if (tid < 64)
    outp[(size_t)bi * 512 + h * 64 + tid] =
        (bf16)(sc[tid] + sc[64 + tid] + sc[128 + tid] + sc[192 + tid]);
}

// ---------------------------------------------------------------- symmetrize lower triangle in place
__global__ __launch_bounds__(256)
void sym_k(float* __restrict__ e) {
  const int i = blockIdx.y + 1;
  const int b = blockIdx.z;
  const int idx = blockIdx.x * 256 + threadIdx.x;  // j*512 + c
  const int j = idx >> 9;
  if (j >= i) return;
  const int c = idx & 511;
  const size_t lo = (((size_t)(b * 128 + i) * 128) + j) * 512 + c;
  const size_t up = (((size_t)(b * 128 + j) * 128) + i) * 512 + c;
  const float u = e[up];
  if (u != 0.0f) e[lo] = u;
}

// ---------------------------------------------------------------- launch
extern "C" void kernel_launch(void* const* d_in, const int* in_sizes, int n_in,
                              void* d_out, int out_size, void* d_ws, size_t ws_size,
                              hipStream_t stream) {
  const float* h_in = (const float*)d_in[0];
  const float* e_in = (const float*)d_in[1];
  const float* Wq   = (const float*)d_in[2];
  const float* Wk   = (const float*)d_in[3];
  const float* Wv   = (const float*)d_in[4];
  const float* We   = (const float*)d_in[5];
  const float* Wni  = (const float*)d_in[6];
  const float* Wnj  = (const float*)d_in[7];
  const float* Woh  = (const float*)d_in[8];
  const float* boh  = (const float*)d_in[9];
  const float* Woe  = (const float*)d_in[10];
  const float* boe  = (const float*)d_in[11];
  const float* bn1g = (const float*)d_in[12];
  const float* bn1b = (const float*)d_in[13];
  const float* bn2g = (const float*)d_in[14];
  const float* bn2b = (const float*)d_in[15];
  const float* ln1g = (const float*)d_in[16];
  const float* ln1b = (const float*)d_in[17];
  const float* ln2g = (const float*)d_in[18];
  const float* ln2b = (const float*)d_in[19];
  const float* fhw1 = (const float*)d_in[20];
  const float* fhw3 = (const float*)d_in[21];
  const float* fhw2 = (const float*)d_in[22];
  const float* few1 = (const float*)d_in[23];
  const float* few3 = (const float*)d_in[24];
  const float* few2 = (const float*)d_in[25];

  char* ws = (char*)d_ws;
  size_t off = 0;
  auto alloc = [&](size_t bytes) -> void* {
    void* p = ws + off;
    off = (off + bytes + 255) & ~(size_t)255;
    return p;
  };

  bf16* qkvT = (bf16*)alloc((size_t)2560 * 512 * 2);
  bf16* WeT  = (bf16*)alloc((size_t)512 * 512 * 2);
  bf16* WohT = (bf16*)alloc((size_t)512 * 512 * 2);
  bf16* WoeT = (bf16*)alloc((size_t)512 * 512 * 2);
  bf16* fh1T = (bf16*)alloc((size_t)2048 * 512 * 2);
  bf16* fh3T = (bf16*)alloc((size_t)2048 * 512 * 2);
  bf16* fh2T = (bf16*)alloc((size_t)512 * 2048 * 2);
  bf16* fe1T = (bf16*)alloc((size_t)2048 * 512 * 2);
  bf16* fe3T = (bf16*)alloc((size_t)2048 * 512 * 2);
  bf16* fe2T = (bf16*)alloc((size_t)512 * 2048 * 2);
  float* h1f = (float*)alloc((size_t)256 * 512 * 4);
  bf16* h1b  = (bf16*)alloc((size_t)256 * 512 * 2);
  float* qkv = (float*)alloc((size_t)256 * 2560 * 4);
  float* h2f = (float*)alloc((size_t)256 * 512 * 4);
  bf16* hxb  = (bf16*)alloc((size_t)256 * 512 * 2);
  bf16* aob  = (bf16*)alloc((size_t)256 * 512 * 2);
  bf16* uhb  = (bf16*)alloc((size_t)256 * 2048 * 2);
  const size_t ER = (size_t)32768 * 512;
  bf16* e1b = (bf16*)alloc(ER * 2);  // e1, later x = LN2(e2)
  bf16* evb = (bf16*)alloc(ER * 2);  // ev; later u-chunk scratch (fallback path)
  bf16* e2b = (bf16*)alloc(ER * 2);

  // full SwiGLU intermediate if workspace allows (128 MB)
  bf16* ufull = nullptr;
  if (off + (size_t)32768 * 2048 * 2 <= ws_size)
    ufull = (bf16*)alloc((size_t)32768 * 2048 * 2);

  float* outh = (float*)d_out;
  float* oute = (float*)d_out + 131072;

  // --- all weight transposes in one dispatch
  TrJobs jobs;
  const float* srcs[14] = {Wq, Wk, Wv, Wni, Wnj, We, Woh, Woe,
                           fhw1, fhw3, fhw2, few1, few3, few2};
  bf16* dsts[14] = {qkvT, qkvT + (size_t)512 * 512, qkvT + (size_t)2 * 512 * 512,
                    qkvT + (size_t)3 * 512 * 512, qkvT + (size_t)4 * 512 * 512,
                    WeT, WohT, WoeT, fh1T, fh3T, fh2T, fe1T, fe3T, fe2T};
  const int Ks[14] = {512, 512, 512, 512, 512, 512, 512, 512,
                      512, 512, 2048, 512, 512, 2048};
  const int Ns[14] = {512, 512, 512, 512, 512, 512, 512, 512,
                      2048, 2048, 512, 2048, 2048, 512};
  for (int w = 0; w < 14; ++w) {
    jobs.src[w] = srcs[w]; jobs.dst[w] = dsts[w];
    jobs.K[w] = Ks[w]; jobs.N[w] = Ns[w];
  }
  transpose_all<<<dim3(1024, 14), 256, 0, stream>>>(jobs);

  // h path front: bn1 -> h1; fused QKV/Ni/Nj projection
  batchnorm_k<<<8, 64, 0, stream>>>(h_in, bn1g, bn1b, h1f, h1b);
  gemm_bt<M_PLAIN><<<dim3(2, 20), 256, 0, stream>>>(
      h1b, qkvT, qkv, 256, 2560, 512, nullptr, nullptr, nullptr);

  // e path: ln1 -> ev = e1@We + Ni + Nj
  layernorm_k<0><<<32768, 128, 0, stream>>>(e_in, ln1g, ln1b, e1b);
  gemm_bt<M_EV><<<dim3(256, 4), 256, 0, stream>>>(
      e1b, WeT, evb, 32768, 512, 512, nullptr, nullptr, qkv);

  // attention -> h2 = h1 + attn@Woh + boh
  attn_k<<<2048, 256, 0, stream>>>(evb, qkv, aob);
  gemm_bt<M_H2><<<dim3(2, 4), 256, 0, stream>>>(
      aob, WohT, h2f, 256, 512, 512, h1f, boh, nullptr);

  // h FFN: bn2 -> dual swiglu -> out_h = h2 + ffn
  batchnorm_k<<<8, 64, 0, stream>>>(h2f, bn2g, bn2b, nullptr, hxb);
  gemm_dual<<<dim3(2, 16), 256, 0, stream>>>(
      hxb, fh1T, fh3T, uhb, 256, 2048, 512);
  gemm_bt<M_RESF><<<dim3(2, 4), 256, 0, stream>>>(
      uhb, fh2T, outh, 256, 512, 2048, h2f, nullptr, nullptr);

  // e2 = e1 + ev@Woe + boe
  gemm_bt<M_E2><<<dim3(256, 4), 256, 0, stream>>>(
      evb, WoeT, e2b, 32768, 512, 512, e1b, boe, nullptr);

  // e FFN: ln2 -> dual swiglu -> out_e = e2 + ffn
  layernorm_k<1><<<32768, 128, 0, stream>>>(e2b, ln2g, ln2b, e1b);
  if (ufull) {
    gemm_dual<<<dim3(256, 16), 256, 0, stream>>>(
        e1b, fe1T, fe3T, ufull, 32768, 2048, 512);
    gemm_bt<M_RESBF><<<dim3(256, 4), 256, 0, stream>>>(
        ufull, fe2T, oute, 32768, 512, 2048, e2b, nullptr, nullptr);
  } else {
    const int R = 8192;  // u chunk reuses evb (exactly 32 MB)
    for (int c = 0; c * R < 32768; ++c) {
      bf16* xA = e1b + (size_t)c * R * 512;
      gemm_dual<<<dim3(R / 128, 16), 256, 0, stream>>>(
          xA, fe1T, fe3T, evb, R, 2048, 512);
      gemm_bt<M_RESBF><<<dim3(R / 128, 4), 256, 0, stream>>>(
          evb, fe2T, oute + (size_t)c * R * 512, R, 512, 2048,
          e2b + (size_t)c * R * 512, nullptr, nullptr);
    }
  }

  sym_k<<<dim3(254, 127, 2), 256, 0, stream>>>(oute);
}

// Round 3
// 781.659 us; speedup vs baseline: 1.2596x; 1.2229x over previous
//
#include <hip/hip_runtime.h>
#include <hip/hip_bf16.h>
#include <cstdint>
#include <cstddef>

#define EPS 1e-5f

typedef __bf16 bf16;
typedef __bf16 bf16x4 __attribute__((ext_vector_type(4)));
typedef __bf16 bf16x8 __attribute__((ext_vector_type(8)));
typedef float f32x4 __attribute__((ext_vector_type(4)));

// ---------------------------------------------------------------- async copy
__device__ inline void async16(const void* g, void* l) {
  __builtin_amdgcn_global_load_lds(
      (const __attribute__((address_space(1))) void*)(uintptr_t)g,
      (__attribute__((address_space(3))) void*)(uint32_t)(uintptr_t)l,
      16, 0, 0);
}

__device__ inline f32x4 mfma_bf16(bf16x8 a, bf16x8 b, f32x4 c) {
  return __builtin_amdgcn_mfma_f32_16x16x32_bf16(a, b, c, 0, 0, 0);
}

// ---------------------------------------------------------------- GEMM
// C[M,N] = A[M,K] * BT[N,K]^T. Grid: (N/BN, M/BM) — n-tile fastest for A reuse.
#define BM 128
#define BN 128
#define BK 32

enum { M_PLAIN = 0, M_EV = 1, M_E2 = 2, M_RESBF = 5, M_H2 = 6, M_RESF = 7 };

template <int MODE>
__global__ __launch_bounds__(256)
void gemm_bt(const bf16* __restrict__ A, const bf16* __restrict__ BT,
             void* __restrict__ outp, int M, int N, int K,
             const void* __restrict__ aux0, const float* __restrict__ aux1,
             const float* __restrict__ qkv) {
  __shared__ bf16 a_lds[BM * BK];
  __shared__ bf16 b_lds[BN * BK];
  const int tid = threadIdx.x;
  const int wave = tid >> 6, lane = tid & 63;
  const int m0 = blockIdx.y * BM, n0 = blockIdx.x * BN;

  const bf16* Ab = A + (size_t)m0 * K;
  const bf16* Bb = BT + (size_t)n0 * K;

  const int srow = tid >> 2;        // 0..63
  const int scol = (tid & 3) * 8;   // 0,8,16,24
  bf16* a_dst0 = &a_lds[(wave * 64) * 8];
  bf16* a_dst1 = &a_lds[(256 + wave * 64) * 8];
  bf16* b_dst0 = &b_lds[(wave * 64) * 8];
  bf16* b_dst1 = &b_lds[(256 + wave * 64) * 8];

  f32x4 acc[4][4] = {};

  const int wm = (wave >> 1) * 64, wn = (wave & 1) * 64;
  const int fr = lane & 15, fq = lane >> 4;

  for (int kt = 0; kt < K; kt += BK) {
    async16(Ab + (size_t)srow * K + kt + scol, a_dst0);
    async16(Ab + (size_t)(srow + 64) * K + kt + scol, a_dst1);
    async16(Bb + (size_t)srow * K + kt + scol, b_dst0);
    async16(Bb + (size_t)(srow + 64) * K + kt + scol, b_dst1);
    __syncthreads();
    bf16x8 af[4], bfv[4];
#pragma unroll
    for (int t = 0; t < 4; ++t) {
      af[t]  = *(const bf16x8*)&a_lds[(wm + t * 16 + fr) * BK + fq * 8];
      bfv[t] = *(const bf16x8*)&b_lds[(wn + t * 16 + fr) * BK + fq * 8];
    }
#pragma unroll
    for (int mt = 0; mt < 4; ++mt)
#pragma unroll
      for (int nt = 0; nt < 4; ++nt)
        acc[mt][nt] = mfma_bf16(af[mt], bfv[nt], acc[mt][nt]);
    __syncthreads();
  }

#pragma unroll
  for (int mt = 0; mt < 4; ++mt) {
#pragma unroll
    for (int r = 0; r < 4; ++r) {
      const int row = m0 + wm + mt * 16 + fq * 4 + r;
#pragma unroll
      for (int nt = 0; nt < 4; ++nt) {
        const int col = n0 + wn + nt * 16 + fr;
        float v = acc[mt][nt][r];
        const size_t oi = (size_t)row * N + col;
        if (MODE == M_PLAIN) {
          ((float*)outp)[oi] = v;
        } else if (MODE == M_EV) {
          const int bi = row >> 7, b = row >> 14, j = row & 127;
          v += qkv[bi * 2560 + 1536 + col] + qkv[(b * 128 + j) * 2560 + 2048 + col];
          ((bf16*)outp)[oi] = (bf16)v;
        } else if (MODE == M_E2) {
          v += (float)((const bf16*)aux0)[oi] + aux1[col];
          ((bf16*)outp)[oi] = (bf16)v;
        } else if (MODE == M_RESBF) {
          ((float*)outp)[oi] = v + (float)((const bf16*)aux0)[oi];
        } else if (MODE == M_H2) {
          ((float*)outp)[oi] = v + ((const float*)aux0)[oi] + aux1[col];
        } else if (MODE == M_RESF) {
          ((float*)outp)[oi] = v + ((const float*)aux0)[oi];
        }
      }
    }
  }
}

// ---------------------------------------------------------------- dual-B SwiGLU GEMM
// out[M,N] = silu(A@B1T^T) * (A@B2T^T), bf16 out.
// Per-B output tile 128x64 (acc 64 regs total) to keep occupancy at 2 waves/SIMD.
// Grid: (N/64, M/128) — n-tile fastest.
__global__ __launch_bounds__(256)
void gemm_dual(const bf16* __restrict__ A, const bf16* __restrict__ B1T,
               const bf16* __restrict__ B2T, bf16* __restrict__ outp,
               int M, int N, int K) {
  __shared__ bf16 a_lds[128 * BK];
  __shared__ bf16 b1_lds[64 * BK];
  __shared__ bf16 b2_lds[64 * BK];
  const int tid = threadIdx.x;
  const int wave = tid >> 6, lane = tid & 63;
  const int m0 = blockIdx.y * 128, n0 = blockIdx.x * 64;

  const bf16* Ab = A + (size_t)m0 * K;
  const bf16* B1b = B1T + (size_t)n0 * K;
  const bf16* B2b = B2T + (size_t)n0 * K;

  const int srow = tid >> 2;        // 0..63
  const int scol = (tid & 3) * 8;
  bf16* a_d0 = &a_lds[(wave * 64) * 8];
  bf16* a_d1 = &a_lds[(256 + wave * 64) * 8];
  bf16* b1_d = &b1_lds[(wave * 64) * 8];
  bf16* b2_d = &b2_lds[(wave * 64) * 8];

  f32x4 acc1[4][2] = {};
  f32x4 acc2[4][2] = {};

  const int wm = (wave >> 1) * 64, wn = (wave & 1) * 32;
  const int fr = lane & 15, fq = lane >> 4;

  for (int kt = 0; kt < K; kt += BK) {
    async16(Ab + (size_t)srow * K + kt + scol, a_d0);
    async16(Ab + (size_t)(srow + 64) * K + kt + scol, a_d1);
    async16(B1b + (size_t)srow * K + kt + scol, b1_d);
    async16(B2b + (size_t)srow * K + kt + scol, b2_d);
    __syncthreads();
    bf16x8 af[4], b1f[2], b2f[2];
#pragma unroll
    for (int t = 0; t < 4; ++t)
      af[t] = *(const bf16x8*)&a_lds[(wm + t * 16 + fr) * BK + fq * 8];
#pragma unroll
    for (int n = 0; n < 2; ++n) {
      b1f[n] = *(const bf16x8*)&b1_lds[(wn + n * 16 + fr) * BK + fq * 8];
      b2f[n] = *(const bf16x8*)&b2_lds[(wn + n * 16 + fr) * BK + fq * 8];
    }
#pragma unroll
    for (int mt = 0; mt < 4; ++mt)
#pragma unroll
      for (int nt = 0; nt < 2; ++nt) {
        acc1[mt][nt] = mfma_bf16(af[mt], b1f[nt], acc1[mt][nt]);
        acc2[mt][nt] = mfma_bf16(af[mt], b2f[nt], acc2[mt][nt]);
      }
    __syncthreads();
  }

#pragma unroll
  for (int mt = 0; mt < 4; ++mt) {
#pragma unroll
    for (int r = 0; r < 4; ++r) {
      const int row = m0 + wm + mt * 16 + fq * 4 + r;
#pragma unroll
      for (int nt = 0; nt < 2; ++nt) {
        const int col = n0 + wn + nt * 16 + fr;
        const float c1 = acc1[mt][nt][r];
        const float c2 = acc2[mt][nt][r];
        const float v = c1 / (1.f + __expf(-c1)) * c2;
        outp[(size_t)row * N + col] = (bf16)v;
      }
    }
  }
}

// ---------------------------------------------------------------- batched transpose
struct TrJobs {
  const float* src[14];
  bf16* dst[14];
  int K[14];
  int N[14];
};

__global__ __launch_bounds__(256)
void transpose_all(TrJobs jobs) {
  const int w = blockIdx.y;
  const int K = jobs.K[w], N = jobs.N[w];
  const int tilesK = K >> 5;
  const int tiles = tilesK * (N >> 5);
  const int t0 = blockIdx.x;
  if (t0 >= tiles) return;
  const int bk = (t0 % tilesK) * 32, bn = (t0 / tilesK) * 32;
  const float* __restrict__ in = jobs.src[w];
  bf16* __restrict__ out = jobs.dst[w];
  __shared__ float t[32][33];
  const int tx = threadIdx.x & 31, ty = threadIdx.x >> 5;  // 32 x 8
#pragma unroll
  for (int r = 0; r < 32; r += 8)
    t[ty + r][tx] = in[(size_t)(bk + ty + r) * N + bn + tx];
  __syncthreads();
#pragma unroll
  for (int r = 0; r < 32; r += 8)
    out[(size_t)(bn + ty + r) * K + bk + tx] = (bf16)t[tx][ty + r];
}

// ---------------------------------------------------------------- batchnorm over 256 rows x 512 ch
__global__ __launch_bounds__(64)
void batchnorm_k(const float* __restrict__ x, const float* __restrict__ g,
                 const float* __restrict__ bta, float* __restrict__ y_f,
                 bf16* __restrict__ y_b) {
  const int c = blockIdx.x * 64 + threadIdx.x;
  float s = 0.f, q = 0.f;
  for (int r = 0; r < 256; ++r) {
    const float v = x[r * 512 + c];
    s += v; q += v * v;
  }
  const float mean = s * (1.f / 256.f);
  const float rstd = rsqrtf(q * (1.f / 256.f) - mean * mean + EPS);
  const float sc = g[c] * rstd, sh = bta[c] - mean * sc;
  for (int r = 0; r < 256; ++r) {
    const float v = x[r * 512 + c] * sc + sh;
    if (y_f) y_f[r * 512 + c] = v;
    y_b[r * 512 + c] = (bf16)v;
  }
}

// ---------------------------------------------------------------- layernorm rows of 512
template <int IN_BF>
__global__ __launch_bounds__(128)
void layernorm_k(const void* __restrict__ xin, const float* __restrict__ g,
                 const float* __restrict__ bta, bf16* __restrict__ yout) {
  const size_t row = blockIdx.x;
  const int tid = threadIdx.x;
  float v[4];
  if (IN_BF) {
    const bf16x4 t = *((const bf16x4*)((const bf16*)xin + row * 512) + tid);
    v[0] = (float)t[0]; v[1] = (float)t[1]; v[2] = (float)t[2]; v[3] = (float)t[3];
  } else {
    const float4 t = *((const float4*)((const float*)xin + row * 512) + tid);
    v[0] = t.x; v[1] = t.y; v[2] = t.z; v[3] = t.w;
  }
  float s = v[0] + v[1] + v[2] + v[3];
  float q = v[0] * v[0] + v[1] * v[1] + v[2] * v[2] + v[3] * v[3];
  for (int o = 32; o > 0; o >>= 1) { s += __shfl_xor(s, o); q += __shfl_xor(q, o); }
  __shared__ float sm[4];
  if ((tid & 63) == 0) { sm[(tid >> 6) * 2] = s; sm[(tid >> 6) * 2 + 1] = q; }
  __syncthreads();
  s = sm[0] + sm[2]; q = sm[1] + sm[3];
  const float mean = s * (1.f / 512.f);
  const float rstd = rsqrtf(q * (1.f / 512.f) - mean * mean + EPS);
  const float4 gg = *((const float4*)g + tid);
  const float4 bb = *((const float4*)bta + tid);
  bf16x4 o4;
  o4[0] = (bf16)((v[0] - mean) * rstd * gg.x + bb.x);
  o4[1] = (bf16)((v[1] - mean) * rstd * gg.y + bb.y);
  o4[2] = (bf16)((v[2] - mean) * rstd * gg.z + bb.z);
  o4[3] = (bf16)((v[3] - mean) * rstd * gg.w + bb.w);
  *((bf16x4*)(yout + row * 512) + tid) = o4;
}

// ---------------------------------------------------------------- attention: 256 threads per (b,h,i)
__global__ __launch_bounds__(256)
void attn_k(const bf16* __restrict__ ev, const float* __restrict__ qkv,
            bf16* __restrict__ outp) {
  const int i = blockIdx.x & 127, h = (blockIdx.x >> 7) & 7, b = blockIdx.x >> 10;
  const int bi = b * 128 + i;
  const int tid = threadIdx.x;
  __shared__ float sc[256];
  __shared__ float wt[128];
  {
    const int j = tid & 127, half = tid >> 7;
    const bf16* evp = ev + (size_t)bi * 65536 + (size_t)j * 512 + h * 64 + half * 32;
    const float* qp = qkv + bi * 2560 + h * 64 + half * 32;
    const float* kp = qkv + (b * 128 + j) * 2560 + 512 + h * 64 + half * 32;
    float p = 0.f;
#pragma unroll
    for (int t = 0; t < 4; ++t) {
      const bf16x8 e8 = *(const bf16x8*)(evp + t * 8);
#pragma unroll
      for (int u = 0; u < 8; ++u)
        p += qp[t * 8 + u] * (float)e8[u] * kp[t * 8 + u];
    }
    sc[half * 128 + j] = p;
  }
  __syncthreads();
  if (tid < 64) {
    const float s0 = (sc[tid] + sc[128 + tid]) * 0.125f;
    const float s1 = (sc[64 + tid] + sc[192 + tid]) * 0.125f;
    float mx = fmaxf(s0, s1);
    for (int o = 32; o > 0; o >>= 1) mx = fmaxf(mx, __shfl_xor(mx, o));
    const float e0 = __expf(s0 - mx), e1 = __expf(s1 - mx);
    float sum = e0 + e1;
    for (int o = 32; o > 0; o >>= 1) sum += __shfl_xor(sum, o);
    const float inv = 1.f / sum;
    wt[tid] = e0 * inv; wt[64 + tid] = e1 * inv;
  }
  __syncthreads();
  {
    const int d = tid & 63, jq = tid >> 6;
    const float* vp = qkv + (b * 128 + jq * 32) * 2560 + 1024 + h * 64 + d;
    float acc = 0.f;
#pragma unroll
    for (int j = 0; j < 32; ++j)
      acc += wt[jq * 32 + j] * vp[(size_t)j * 2560];
    sc[tid] = acc;
  }
  __syncthreads();
  if (tid < 64)
    outp[(size_t)bi * 512 + h * 64 + tid] =
        (bf16)(sc[tid] + sc[64 + tid] + sc[128 + tid] + sc[192 + tid]);
}

// ---------------------------------------------------------------- symmetrize lower triangle in place
__global__ __launch_bounds__(256)
void sym_k(float* __restrict__ e) {
  const int i = blockIdx.y + 1;
  const int b = blockIdx.z;
  const int idx = blockIdx.x * 256 + threadIdx.x;  // j*512 + c
  const int j = idx >> 9;
  if (j >= i) return;
  const int c = idx & 511;
  const size_t lo = (((size_t)(b * 128 + i) * 128) + j) * 512 + c;
  const size_t up = (((size_t)(b * 128 + j) * 128) + i) * 512 + c;
  const float u = e[up];
  if (u != 0.0f) e[lo] = u;
}

// ---------------------------------------------------------------- launch
extern "C" void kernel_launch(void* const* d_in, const int* in_sizes, int n_in,
                              void* d_out, int out_size, void* d_ws, size_t ws_size,
                              hipStream_t stream) {
  const float* h_in = (const float*)d_in[0];
  const float* e_in = (const float*)d_in[1];
  const float* Wq   = (const float*)d_in[2];
  const float* Wk   = (const float*)d_in[3];
  const float* Wv   = (const float*)d_in[4];
  const float* We   = (const float*)d_in[5];
  const float* Wni  = (const float*)d_in[6];
  const float* Wnj  = (const float*)d_in[7];
  const float* Woh  = (const float*)d_in[8];
  const float* boh  = (const float*)d_in[9];
  const float* Woe  = (const float*)d_in[10];
  const float* boe  = (const float*)d_in[11];
  const float* bn1g = (const float*)d_in[12];
  const float* bn1b = (const float*)d_in[13];
  const float* bn2g = (const float*)d_in[14];
  const float* bn2b = (const float*)d_in[15];
  const float* ln1g = (const float*)d_in[16];
  const float* ln1b = (const float*)d_in[17];
  const float* ln2g = (const float*)d_in[18];
  const float* ln2b = (const float*)d_in[19];
  const float* fhw1 = (const float*)d_in[20];
  const float* fhw3 = (const float*)d_in[21];
  const float* fhw2 = (const float*)d_in[22];
  const float* few1 = (const float*)d_in[23];
  const float* few3 = (const float*)d_in[24];
  const float* few2 = (const float*)d_in[25];

  char* ws = (char*)d_ws;
  size_t off = 0;
  auto alloc = [&](size_t bytes) -> void* {
    void* p = ws + off;
    off = (off + bytes + 255) & ~(size_t)255;
    return p;
  };

  bf16* qkvT = (bf16*)alloc((size_t)2560 * 512 * 2);
  bf16* WeT  = (bf16*)alloc((size_t)512 * 512 * 2);
  bf16* WohT = (bf16*)alloc((size_t)512 * 512 * 2);
  bf16* WoeT = (bf16*)alloc((size_t)512 * 512 * 2);
  bf16* fh1T = (bf16*)alloc((size_t)2048 * 512 * 2);
  bf16* fh3T = (bf16*)alloc((size_t)2048 * 512 * 2);
  bf16* fh2T = (bf16*)alloc((size_t)512 * 2048 * 2);
  bf16* fe1T = (bf16*)alloc((size_t)2048 * 512 * 2);
  bf16* fe3T = (bf16*)alloc((size_t)2048 * 512 * 2);
  bf16* fe2T = (bf16*)alloc((size_t)512 * 2048 * 2);
  float* h1f = (float*)alloc((size_t)256 * 512 * 4);
  bf16* h1b  = (bf16*)alloc((size_t)256 * 512 * 2);
  float* qkv = (float*)alloc((size_t)256 * 2560 * 4);
  float* h2f = (float*)alloc((size_t)256 * 512 * 4);
  bf16* hxb  = (bf16*)alloc((size_t)256 * 512 * 2);
  bf16* aob  = (bf16*)alloc((size_t)256 * 512 * 2);
  bf16* uhb  = (bf16*)alloc((size_t)256 * 2048 * 2);
  const size_t ER = (size_t)32768 * 512;
  bf16* e1b = (bf16*)alloc(ER * 2);  // e1, later x = LN2(e2)
  bf16* evb = (bf16*)alloc(ER * 2);  // ev; later u-chunk scratch (fallback path)
  bf16* e2b = (bf16*)alloc(ER * 2);

  bf16* ufull = nullptr;
  if (off + (size_t)32768 * 2048 * 2 <= ws_size)
    ufull = (bf16*)alloc((size_t)32768 * 2048 * 2);

  float* outh = (float*)d_out;
  float* oute = (float*)d_out + 131072;

  // --- all weight transposes in one dispatch
  TrJobs jobs;
  const float* srcs[14] = {Wq, Wk, Wv, Wni, Wnj, We, Woh, Woe,
                           fhw1, fhw3, fhw2, few1, few3, few2};
  bf16* dsts[14] = {qkvT, qkvT + (size_t)512 * 512, qkvT + (size_t)2 * 512 * 512,
                    qkvT + (size_t)3 * 512 * 512, qkvT + (size_t)4 * 512 * 512,
                    WeT, WohT, WoeT, fh1T, fh3T, fh2T, fe1T, fe3T, fe2T};
  const int Ks[14] = {512, 512, 512, 512, 512, 512, 512, 512,
                      512, 512, 2048, 512, 512, 2048};
  const int Ns[14] = {512, 512, 512, 512, 512, 512, 512, 512,
                      2048, 2048, 512, 2048, 2048, 512};
  for (int w = 0; w < 14; ++w) {
    jobs.src[w] = srcs[w]; jobs.dst[w] = dsts[w];
    jobs.K[w] = Ks[w]; jobs.N[w] = Ns[w];
  }
  transpose_all<<<dim3(1024, 14), 256, 0, stream>>>(jobs);

  // h path front: bn1 -> h1; fused QKV/Ni/Nj projection
  batchnorm_k<<<8, 64, 0, stream>>>(h_in, bn1g, bn1b, h1f, h1b);
  gemm_bt<M_PLAIN><<<dim3(20, 2), 256, 0, stream>>>(
      h1b, qkvT, qkv, 256, 2560, 512, nullptr, nullptr, nullptr);

  // e path: ln1 -> ev = e1@We + Ni + Nj
  layernorm_k<0><<<32768, 128, 0, stream>>>(e_in, ln1g, ln1b, e1b);
  gemm_bt<M_EV><<<dim3(4, 256), 256, 0, stream>>>(
      e1b, WeT, evb, 32768, 512, 512, nullptr, nullptr, qkv);

  // attention -> h2 = h1 + attn@Woh + boh
  attn_k<<<2048, 256, 0, stream>>>(evb, qkv, aob);
  gemm_bt<M_H2><<<dim3(4, 2), 256, 0, stream>>>(
      aob, WohT, h2f, 256, 512, 512, h1f, boh, nullptr);

  // h FFN: bn2 -> dual swiglu -> out_h = h2 + ffn
  batchnorm_k<<<8, 64, 0, stream>>>(h2f, bn2g, bn2b, nullptr, hxb);
  gemm_dual<<<dim3(32, 2), 256, 0, stream>>>(
      hxb, fh1T, fh3T, uhb, 256, 2048, 512);
  gemm_bt<M_RESF><<<dim3(4, 2), 256, 0, stream>>>(
      uhb, fh2T, outh, 256, 512, 2048, h2f, nullptr, nullptr);

  // e2 = e1 + ev@Woe + boe
  gemm_bt<M_E2><<<dim3(4, 256), 256, 0, stream>>>(
      evb, WoeT, e2b, 32768, 512, 512, e1b, boe, nullptr);

  // e FFN: ln2 -> dual swiglu -> out_e = e2 + ffn
  layernorm_k<1><<<32768, 128, 0, stream>>>(e2b, ln2g, ln2b, e1b);
  if (ufull) {
    gemm_dual<<<dim3(32, 256), 256, 0, stream>>>(
        e1b, fe1T, fe3T, ufull, 32768, 2048, 512);
    gemm_bt<M_RESBF><<<dim3(4, 256), 256, 0, stream>>>(
        ufull, fe2T, oute, 32768, 512, 2048, e2b, nullptr, nullptr);
  } else {
    const int R = 8192;  // u chunk reuses evb (exactly 32 MB)
    for (int c = 0; c * R < 32768; ++c) {
      bf16* xA = e1b + (size_t)c * R * 512;
      gemm_dual<<<dim3(32, R / 128), 256, 0, stream>>>(
          xA, fe1T, fe3T, evb, R, 2048, 512);
      gemm_bt<M_RESBF><<<dim3(4, R / 128), 256, 0, stream>>>(
          evb, fe2T, oute + (size_t)c * R * 512, R, 512, 2048,
          e2b + (size_t)c * R * 512, nullptr, nullptr);
    }
  }

  sym_k<<<dim3(254, 127, 2), 256, 0, stream>>>(oute);
}

// Round 4
// 619.366 us; speedup vs baseline: 1.5897x; 1.2620x over previous
//
#include <hip/hip_runtime.h>
#include <hip/hip_bf16.h>
#include <cstdint>
#include <cstddef>

#define EPS 1e-5f
#define PB 8320    // padded packed rows per batch (65 tiles of 128)
#define PBV 8256   // valid upper-triangle rows per batch (i<=j)

typedef __bf16 bf16;
typedef __bf16 bf16x4 __attribute__((ext_vector_type(4)));
typedef __bf16 bf16x8 __attribute__((ext_vector_type(8)));
typedef float f32x4 __attribute__((ext_vector_type(4)));

// ---------------------------------------------------------------- async copy
__device__ inline void async16(const void* g, void* l) {
  __builtin_amdgcn_global_load_lds(
      (const __attribute__((address_space(1))) void*)(uintptr_t)g,
      (__attribute__((address_space(3))) void*)(uint32_t)(uintptr_t)l,
      16, 0, 0);
}

__device__ inline f32x4 mfma_bf16(bf16x8 a, bf16x8 b, f32x4 c) {
  return __builtin_amdgcn_mfma_f32_16x16x32_bf16(a, b, c, 0, 0, 0);
}

// ---------------------------------------------------------------- packed-row table
// tbl[p] = (i<<8)|j for packed upper row p (j>=i), 0xFFFFFFFF for pad
__global__ __launch_bounds__(256)
void build_tbl(uint32_t* __restrict__ tbl) {
  const int p = blockIdx.x * 256 + threadIdx.x;
  if (p >= PB) return;
  if (p >= PBV) { tbl[p] = 0xFFFFFFFFu; return; }
  int i = 0, o = 0;
  while (o + (128 - i) <= p) { o += 128 - i; ++i; }
  tbl[p] = (uint32_t)((i << 8) | (i + (p - o)));
}

// ---------------------------------------------------------------- GEMM
// C[M,N] = A[M,K] * BT[N,K]^T. Grid: (N/BN, M/BM) — n-tile fastest for A reuse.
#define BM 128
#define BN 128
#define BK 32

enum { M_PLAIN = 0, M_EV = 1, M_E2G = 2, M_H2 = 3, M_RESF = 4, M_SYM = 5 };

template <int MODE>
__global__ __launch_bounds__(256)
void gemm_bt(const bf16* __restrict__ A, const bf16* __restrict__ BT,
             void* __restrict__ outp, int M, int N, int K,
             const void* __restrict__ aux0, const float* __restrict__ aux1,
             const float* __restrict__ qkv, const uint32_t* __restrict__ tbl) {
  __shared__ bf16 a_lds[BM * BK];
  __shared__ bf16 b_lds[BN * BK];
  const int tid = threadIdx.x;
  const int wave = tid >> 6, lane = tid & 63;
  const int m0 = blockIdx.y * BM, n0 = blockIdx.x * BN;

  const int srow = tid >> 2;        // 0..63
  const int scol = (tid & 3) * 8;   // 0,8,16,24

  // resolve A row indices (gathered for M_E2G: packed row -> full ev row)
  size_t arow0, arow1;
  if (MODE == M_E2G) {
    auto gmap = [&](int r) -> size_t {
      const int b = (r >= PB) ? 1 : 0;
      const uint32_t t = tbl[r - b * PB];
      if (t == 0xFFFFFFFFu) return 0;
      return ((size_t)(b * 128 + (int)(t >> 8)) * 128 + (int)(t & 255));
    };
    arow0 = gmap(m0 + srow);
    arow1 = gmap(m0 + srow + 64);
  } else {
    arow0 = (size_t)(m0 + srow);
    arow1 = (size_t)(m0 + srow + 64);
  }
  const bf16* ap0 = A + arow0 * K;
  const bf16* ap1 = A + arow1 * K;
  const bf16* bp0 = BT + (size_t)(n0 + srow) * K;
  const bf16* bp1 = BT + (size_t)(n0 + srow + 64) * K;

  bf16* a_dst0 = &a_lds[(wave * 64) * 8];
  bf16* a_dst1 = &a_lds[(256 + wave * 64) * 8];
  bf16* b_dst0 = &b_lds[(wave * 64) * 8];
  bf16* b_dst1 = &b_lds[(256 + wave * 64) * 8];

  f32x4 acc[4][4] = {};

  const int wm = (wave >> 1) * 64, wn = (wave & 1) * 64;
  const int fr = lane & 15, fq = lane >> 4;

  for (int kt = 0; kt < K; kt += BK) {
    async16(ap0 + kt + scol, a_dst0);
    async16(ap1 + kt + scol, a_dst1);
    async16(bp0 + kt + scol, b_dst0);
    async16(bp1 + kt + scol, b_dst1);
    __syncthreads();
    bf16x8 af[4], bfv[4];
#pragma unroll
    for (int t = 0; t < 4; ++t) {
      af[t]  = *(const bf16x8*)&a_lds[(wm + t * 16 + fr) * BK + fq * 8];
      bfv[t] = *(const bf16x8*)&b_lds[(wn + t * 16 + fr) * BK + fq * 8];
    }
#pragma unroll
    for (int mt = 0; mt < 4; ++mt)
#pragma unroll
      for (int nt = 0; nt < 4; ++nt)
        acc[mt][nt] = mfma_bf16(af[mt], bfv[nt], acc[mt][nt]);
    __syncthreads();
  }

#pragma unroll
  for (int mt = 0; mt < 4; ++mt) {
#pragma unroll
    for (int r = 0; r < 4; ++r) {
      const int row = m0 + wm + mt * 16 + fq * 4 + r;
      // per-row packed decode (hoisted out of nt loop)
      int pb = 0, pi = 0, pj = 0;
      bool valid = true;
      if (MODE == M_E2G || MODE == M_SYM) {
        pb = (row >= PB) ? 1 : 0;
        const uint32_t t = tbl[row - pb * PB];
        valid = (t != 0xFFFFFFFFu);
        pi = (int)(t >> 8); pj = (int)(t & 255);
      }
#pragma unroll
      for (int nt = 0; nt < 4; ++nt) {
        const int col = n0 + wn + nt * 16 + fr;
        float v = acc[mt][nt][r];
        const size_t oi = (size_t)row * N + col;
        if (MODE == M_PLAIN) {
          ((float*)outp)[oi] = v;
        } else if (MODE == M_EV) {
          const int bi = row >> 7, b = row >> 14, j = row & 127;
          v += qkv[bi * 2560 + 1536 + col] + qkv[(b * 128 + j) * 2560 + 2048 + col];
          ((bf16*)outp)[oi] = (bf16)v;
        } else if (MODE == M_E2G) {
          // e2_packed = e1[full row] + ev@Woe + boe
          const size_t g = valid
              ? ((size_t)(pb * 128 + pi) * 128 + pj) : 0;
          v += (float)((const bf16*)aux0)[g * 512 + col] + aux1[col];
          ((bf16*)outp)[oi] = (bf16)v;
        } else if (MODE == M_H2) {
          ((float*)outp)[oi] = v + ((const float*)aux0)[oi] + aux1[col];
        } else if (MODE == M_RESF) {
          ((float*)outp)[oi] = v + ((const float*)aux0)[oi];
        } else if (MODE == M_SYM) {
          // final e out: v + e2_packed, scattered to (i,j) and (j,i)
          if (valid) {
            const float v2 = v + (float)((const bf16*)aux0)[oi];
            ((float*)outp)[(((size_t)(pb * 128 + pi) * 128) + pj) * 512 + col] = v2;
            ((float*)outp)[(((size_t)(pb * 128 + pj) * 128) + pi) * 512 + col] = v2;
          }
        }
      }
    }
  }
}

// ---------------------------------------------------------------- dual-B SwiGLU GEMM
// out[M,N] = silu(A@B1T^T) * (A@B2T^T), bf16 out. Per-B tile 128x64.
// Grid: (N/64, M/128) — n-tile fastest.
__global__ __launch_bounds__(256)
void gemm_dual(const bf16* __restrict__ A, const bf16* __restrict__ B1T,
               const bf16* __restrict__ B2T, bf16* __restrict__ outp,
               int M, int N, int K) {
  __shared__ bf16 a_lds[128 * BK];
  __shared__ bf16 b1_lds[64 * BK];
  __shared__ bf16 b2_lds[64 * BK];
  const int tid = threadIdx.x;
  const int wave = tid >> 6, lane = tid & 63;
  const int m0 = blockIdx.y * 128, n0 = blockIdx.x * 64;

  const bf16* Ab = A + (size_t)m0 * K;
  const bf16* B1b = B1T + (size_t)n0 * K;
  const bf16* B2b = B2T + (size_t)n0 * K;

  const int srow = tid >> 2;
  const int scol = (tid & 3) * 8;
  bf16* a_d0 = &a_lds[(wave * 64) * 8];
  bf16* a_d1 = &a_lds[(256 + wave * 64) * 8];
  bf16* b1_d = &b1_lds[(wave * 64) * 8];
  bf16* b2_d = &b2_lds[(wave * 64) * 8];

  f32x4 acc1[4][2] = {};
  f32x4 acc2[4][2] = {};

  const int wm = (wave >> 1) * 64, wn = (wave & 1) * 32;
  const int fr = lane & 15, fq = lane >> 4;

  for (int kt = 0; kt < K; kt += BK) {
    async16(Ab + (size_t)srow * K + kt + scol, a_d0);
    async16(Ab + (size_t)(srow + 64) * K + kt + scol, a_d1);
    async16(B1b + (size_t)srow * K + kt + scol, b1_d);
    async16(B2b + (size_t)srow * K + kt + scol, b2_d);
    __syncthreads();
    bf16x8 af[4], b1f[2], b2f[2];
#pragma unroll
    for (int t = 0; t < 4; ++t)
      af[t] = *(const bf16x8*)&a_lds[(wm + t * 16 + fr) * BK + fq * 8];
#pragma unroll
    for (int n = 0; n < 2; ++n) {
      b1f[n] = *(const bf16x8*)&b1_lds[(wn + n * 16 + fr) * BK + fq * 8];
      b2f[n] = *(const bf16x8*)&b2_lds[(wn + n * 16 + fr) * BK + fq * 8];
    }
#pragma unroll
    for (int mt = 0; mt < 4; ++mt)
#pragma unroll
      for (int nt = 0; nt < 2; ++nt) {
        acc1[mt][nt] = mfma_bf16(af[mt], b1f[nt], acc1[mt][nt]);
        acc2[mt][nt] = mfma_bf16(af[mt], b2f[nt], acc2[mt][nt]);
      }
    __syncthreads();
  }

#pragma unroll
  for (int mt = 0; mt < 4; ++mt) {
#pragma unroll
    for (int r = 0; r < 4; ++r) {
      const int row = m0 + wm + mt * 16 + fq * 4 + r;
#pragma unroll
      for (int nt = 0; nt < 2; ++nt) {
        const int col = n0 + wn + nt * 16 + fr;
        const float c1 = acc1[mt][nt][r];
        const float c2 = acc2[mt][nt][r];
        const float v = c1 / (1.f + __expf(-c1)) * c2;
        outp[(size_t)row * N + col] = (bf16)v;
      }
    }
  }
}

// ---------------------------------------------------------------- batched transpose
struct TrJobs {
  const float* src[14];
  bf16* dst[14];
  int K[14];
  int N[14];
};

__global__ __launch_bounds__(256)
void transpose_all(TrJobs jobs) {
  const int w = blockIdx.y;
  const int K = jobs.K[w], N = jobs.N[w];
  const int tilesK = K >> 5;
  const int tiles = tilesK * (N >> 5);
  const int t0 = blockIdx.x;
  if (t0 >= tiles) return;
  const int bk = (t0 % tilesK) * 32, bn = (t0 / tilesK) * 32;
  const float* __restrict__ in = jobs.src[w];
  bf16* __restrict__ out = jobs.dst[w];
  __shared__ float t[32][33];
  const int tx = threadIdx.x & 31, ty = threadIdx.x >> 5;  // 32 x 8
#pragma unroll
  for (int r = 0; r < 32; r += 8)
    t[ty + r][tx] = in[(size_t)(bk + ty + r) * N + bn + tx];
  __syncthreads();
#pragma unroll
  for (int r = 0; r < 32; r += 8)
    out[(size_t)(bn + ty + r) * K + bk + tx] = (bf16)t[tx][ty + r];
}

// ---------------------------------------------------------------- batchnorm over 256 rows x 512 ch
__global__ __launch_bounds__(64)
void batchnorm_k(const float* __restrict__ x, const float* __restrict__ g,
                 const float* __restrict__ bta, float* __restrict__ y_f,
                 bf16* __restrict__ y_b) {
  const int c = blockIdx.x * 64 + threadIdx.x;
  float s = 0.f, q = 0.f;
  for (int r = 0; r < 256; ++r) {
    const float v = x[r * 512 + c];
    s += v; q += v * v;
  }
  const float mean = s * (1.f / 256.f);
  const float rstd = rsqrtf(q * (1.f / 256.f) - mean * mean + EPS);
  const float sc = g[c] * rstd, sh = bta[c] - mean * sc;
  for (int r = 0; r < 256; ++r) {
    const float v = x[r * 512 + c] * sc + sh;
    if (y_f) y_f[r * 512 + c] = v;
    y_b[r * 512 + c] = (bf16)v;
  }
}

// ---------------------------------------------------------------- layernorm rows of 512
template <int IN_BF>
__global__ __launch_bounds__(128)
void layernorm_k(const void* __restrict__ xin, const float* __restrict__ g,
                 const float* __restrict__ bta, bf16* __restrict__ yout) {
  const size_t row = blockIdx.x;
  const int tid = threadIdx.x;
  float v[4];
  if (IN_BF) {
    const bf16x4 t = *((const bf16x4*)((const bf16*)xin + row * 512) + tid);
    v[0] = (float)t[0]; v[1] = (float)t[1]; v[2] = (float)t[2]; v[3] = (float)t[3];
  } else {
    const float4 t = *((const float4*)((const float*)xin + row * 512) + tid);
    v[0] = t.x; v[1] = t.y; v[2] = t.z; v[3] = t.w;
  }
  float s = v[0] + v[1] + v[2] + v[3];
  float q = v[0] * v[0] + v[1] * v[1] + v[2] * v[2] + v[3] * v[3];
  for (int o = 32; o > 0; o >>= 1) { s += __shfl_xor(s, o); q += __shfl_xor(q, o); }
  __shared__ float sm[4];
  if ((tid & 63) == 0) { sm[(tid >> 6) * 2] = s; sm[(tid >> 6) * 2 + 1] = q; }
  __syncthreads();
  s = sm[0] + sm[2]; q = sm[1] + sm[3];
  const float mean = s * (1.f / 512.f);
  const float rstd = rsqrtf(q * (1.f / 512.f) - mean * mean + EPS);
  const float4 gg = *((const float4*)g + tid);
  const float4 bb = *((const float4*)bta + tid);
  bf16x4 o4;
  o4[0] = (bf16)((v[0] - mean) * rstd * gg.x + bb.x);
  o4[1] = (bf16)((v[1] - mean) * rstd * gg.y + bb.y);
  o4[2] = (bf16)((v[2] - mean) * rstd * gg.z + bb.z);
  o4[3] = (bf16)((v[3] - mean) * rstd * gg.w + bb.w);
  *((bf16x4*)(yout + row * 512) + tid) = o4;
}

// ---------------------------------------------------------------- attention: 256 threads per (b,h,i)
__global__ __launch_bounds__(256)
void attn_k(const bf16* __restrict__ ev, const float* __restrict__ qkv,
            bf16* __restrict__ outp) {
  const int i = blockIdx.x & 127, h = (blockIdx.x >> 7) & 7, b = blockIdx.x >> 10;
  const int bi = b * 128 + i;
  const int tid = threadIdx.x;
  __shared__ float sc[256];
  __shared__ float wt[128];
  {
    const int j = tid & 127, half = tid >> 7;
    const bf16* evp = ev + (size_t)bi * 65536 + (size_t)j * 512 + h * 64 + half * 32;
    const float* qp = qkv + bi * 2560 + h * 64 + half * 32;
    const float* kp = qkv + (b * 128 + j) * 2560 + 512 + h * 64 + half * 32;
    float p = 0.f;
#pragma unroll
    for (int t = 0; t < 4; ++t) {
      const bf16x8 e8 = *(const bf16x8*)(evp + t * 8);
#pragma unroll
      for (int u = 0; u < 8; ++u)
        p += qp[t * 8 + u] * (float)e8[u] * kp[t * 8 + u];
    }
    sc[half * 128 + j] = p;
  }
  __syncthreads();
  if (tid < 64) {
    const float s0 = (sc[tid] + sc[128 + tid]) * 0.125f;
    const float s1 = (sc[64 + tid] + sc[192 + tid]) * 0.125f;
    float mx = fmaxf(s0, s1);
    for (int o = 32; o > 0; o >>= 1) mx = fmaxf(mx, __shfl_xor(mx, o));
    const float e0 = __expf(s0 - mx), e1 = __expf(s1 - mx);
    float sum = e0 + e1;
    for (int o = 32; o > 0; o >>= 1) sum += __shfl_xor(sum, o);
    const float inv = 1.f / sum;
    wt[tid] = e0 * inv; wt[64 + tid] = e1 * inv;
  }
  __syncthreads();
  {
    const int d = tid & 63, jq = tid >> 6;
    const float* vp = qkv + (b * 128 + jq * 32) * 2560 + 1024 + h * 64 + d;
    float acc = 0.f;
#pragma unroll
    for (int j = 0; j < 32; ++j)
      acc += wt[jq * 32 + j] * vp[(size_t)j * 2560];
    sc[tid] = acc;
  }
  __syncthreads();
  if (tid < 64)
    outp[(size_t)bi * 512 + h * 64 + tid] =
        (bf16)(sc[tid] + sc[64 + tid] + sc[128 + tid] + sc[192 + tid]);
}

// ---------------------------------------------------------------- launch
extern "C" void kernel_launch(void* const* d_in, const int* in_sizes, int n_in,
                              void* d_out, int out_size, void* d_ws, size_t ws_size,
                              hipStream_t stream) {
  const float* h_in = (const float*)d_in[0];
  const float* e_in = (const float*)d_in[1];
  const float* Wq   = (const float*)d_in[2];
  const float* Wk   = (const float*)d_in[3];
  const float* Wv   = (const float*)d_in[4];
  const float* We   = (const float*)d_in[5];
  const float* Wni  = (const float*)d_in[6];
  const float* Wnj  = (const float*)d_in[7];
  const float* Woh  = (const float*)d_in[8];
  const float* boh  = (const float*)d_in[9];
  const float* Woe  = (const float*)d_in[10];
  const float* boe  = (const float*)d_in[11];
  const float* bn1g = (const float*)d_in[12];
  const float* bn1b = (const float*)d_in[13];
  const float* bn2g = (const float*)d_in[14];
  const float* bn2b = (const float*)d_in[15];
  const float* ln1g = (const float*)d_in[16];
  const float* ln1b = (const float*)d_in[17];
  const float* ln2g = (const float*)d_in[18];
  const float* ln2b = (const float*)d_in[19];
  const float* fhw1 = (const float*)d_in[20];
  const float* fhw3 = (const float*)d_in[21];
  const float* fhw2 = (const float*)d_in[22];
  const float* few1 = (const float*)d_in[23];
  const float* few3 = (const float*)d_in[24];
  const float* few2 = (const float*)d_in[25];

  char* ws = (char*)d_ws;
  size_t off = 0;
  auto alloc = [&](size_t bytes) -> void* {
    void* p = ws + off;
    off = (off + bytes + 255) & ~(size_t)255;
    return p;
  };

  bf16* qkvT = (bf16*)alloc((size_t)2560 * 512 * 2);
  bf16* WeT  = (bf16*)alloc((size_t)512 * 512 * 2);
  bf16* WohT = (bf16*)alloc((size_t)512 * 512 * 2);
  bf16* WoeT = (bf16*)alloc((size_t)512 * 512 * 2);
  bf16* fh1T = (bf16*)alloc((size_t)2048 * 512 * 2);
  bf16* fh3T = (bf16*)alloc((size_t)2048 * 512 * 2);
  bf16* fh2T = (bf16*)alloc((size_t)512 * 2048 * 2);
  bf16* fe1T = (bf16*)alloc((size_t)2048 * 512 * 2);
  bf16* fe3T = (bf16*)alloc((size_t)2048 * 512 * 2);
  bf16* fe2T = (bf16*)alloc((size_t)512 * 2048 * 2);
  uint32_t* tbl = (uint32_t*)alloc((size_t)PB * 4);
  float* h1f = (float*)alloc((size_t)256 * 512 * 4);
  bf16* h1b  = (bf16*)alloc((size_t)256 * 512 * 2);
  float* qkv = (float*)alloc((size_t)256 * 2560 * 4);
  float* h2f = (float*)alloc((size_t)256 * 512 * 4);
  bf16* hxb  = (bf16*)alloc((size_t)256 * 512 * 2);
  bf16* aob  = (bf16*)alloc((size_t)256 * 512 * 2);
  bf16* uhb  = (bf16*)alloc((size_t)256 * 2048 * 2);
  const int MP = 2 * PB;                      // 16640 packed rows
  bf16* e1b = (bf16*)alloc((size_t)32768 * 512 * 2);  // e1 full; later LN2 out (packed)
  bf16* evb = (bf16*)alloc((size_t)32768 * 512 * 2);  // ev full
  bf16* e2b = (bf16*)alloc((size_t)MP * 512 * 2);     // e2 packed
  bf16* ufull = (bf16*)alloc((size_t)MP * 2048 * 2);  // swiglu intermediate packed

  float* outh = (float*)d_out;
  float* oute = (float*)d_out + 131072;

  // --- all weight transposes in one dispatch + packed-row table
  TrJobs jobs;
  const float* srcs[14] = {Wq, Wk, Wv, Wni, Wnj, We, Woh, Woe,
                           fhw1, fhw3, fhw2, few1, few3, few2};
  bf16* dsts[14] = {qkvT, qkvT + (size_t)512 * 512, qkvT + (size_t)2 * 512 * 512,
                    qkvT + (size_t)3 * 512 * 512, qkvT + (size_t)4 * 512 * 512,
                    WeT, WohT, WoeT, fh1T, fh3T, fh2T, fe1T, fe3T, fe2T};
  const int Ks[14] = {512, 512, 512, 512, 512, 512, 512, 512,
                      512, 512, 2048, 512, 512, 2048};
  const int Ns[14] = {512, 512, 512, 512, 512, 512, 512, 512,
                      2048, 2048, 512, 2048, 2048, 512};
  for (int w = 0; w < 14; ++w) {
    jobs.src[w] = srcs[w]; jobs.dst[w] = dsts[w];
    jobs.K[w] = Ks[w]; jobs.N[w] = Ns[w];
  }
  transpose_all<<<dim3(1024, 14), 256, 0, stream>>>(jobs);
  build_tbl<<<(PB + 255) / 256, 256, 0, stream>>>(tbl);

  // h path front: bn1 -> h1; fused QKV/Ni/Nj projection
  batchnorm_k<<<8, 64, 0, stream>>>(h_in, bn1g, bn1b, h1f, h1b);
  gemm_bt<M_PLAIN><<<dim3(20, 2), 256, 0, stream>>>(
      h1b, qkvT, qkv, 256, 2560, 512, nullptr, nullptr, nullptr, nullptr);

  // e path: ln1 -> ev = e1@We + Ni + Nj (full, feeds attention)
  layernorm_k<0><<<32768, 128, 0, stream>>>(e_in, ln1g, ln1b, e1b);
  gemm_bt<M_EV><<<dim3(4, 256), 256, 0, stream>>>(
      e1b, WeT, evb, 32768, 512, 512, nullptr, nullptr, qkv, nullptr);

  // attention -> h2 = h1 + attn@Woh + boh
  attn_k<<<2048, 256, 0, stream>>>(evb, qkv, aob);
  gemm_bt<M_H2><<<dim3(4, 2), 256, 0, stream>>>(
      aob, WohT, h2f, 256, 512, 512, h1f, boh, nullptr, nullptr);

  // h FFN: bn2 -> dual swiglu -> out_h = h2 + ffn
  batchnorm_k<<<8, 64, 0, stream>>>(h2f, bn2g, bn2b, nullptr, hxb);
  gemm_dual<<<dim3(32, 2), 256, 0, stream>>>(
      hxb, fh1T, fh3T, uhb, 256, 2048, 512);
  gemm_bt<M_RESF><<<dim3(4, 2), 256, 0, stream>>>(
      uhb, fh2T, outh, 256, 512, 2048, h2f, nullptr, nullptr, nullptr);

  // e2 (PACKED upper rows) = e1 + ev@Woe + boe — A rows gathered via tbl
  gemm_bt<M_E2G><<<dim3(4, MP / 128), 256, 0, stream>>>(
      evb, WoeT, e2b, MP, 512, 512, e1b, boe, nullptr, tbl);

  // e FFN (packed): ln2 -> dual swiglu -> out_e scattered to (i,j) and (j,i)
  layernorm_k<1><<<MP, 128, 0, stream>>>(e2b, ln2g, ln2b, e1b);
  gemm_dual<<<dim3(32, MP / 128), 256, 0, stream>>>(
      e1b, fe1T, fe3T, ufull, MP, 2048, 512);
  gemm_bt<M_SYM><<<dim3(4, MP / 128), 256, 0, stream>>>(
      ufull, fe2T, oute, MP, 512, 2048, e2b, nullptr, nullptr, tbl);
}